// Round 1
// baseline (489.217 us; speedup 1.0000x reference)
//
#include <hip/hip_runtime.h>
#include <math.h>

// Problem constants
constexpr int B = 8;
constexpr int D = 256;     // model dim
constexpr int C = 1024;    // expanded channels
constexpr int H = 32, W = 32;
constexpr int P = H * W;            // 1024 spatial positions
constexpr int M = B * P;            // 8192 rows
constexpr float EPS = 1e-5f;

// ---------------- workspace layout (in floats) ----------------
// zeroed accumulator region
constexpr size_t WS_CHSUM1 = 0;                  // 1024
constexpr size_t WS_CHSQ1  = 1024;               // 1024
constexpr size_t WS_GAPSUM = 2048;               // 8192
constexpr size_t WS_CHSUM3 = 10240;              // 256
constexpr size_t WS_CHSQ3  = 10496;              // 256
constexpr size_t WS_ACC_COUNT = 10752;           // total zeroed floats
// non-zeroed
constexpr size_t WS_SCALE1 = 11264;              // 1024
constexpr size_t WS_SHIFT1 = 12288;              // 1024
constexpr size_t WS_GAP    = 13312;              // 8192
constexpr size_t WS_KW     = 21504;              // 72 (pad)
constexpr size_t WS_SCALE2 = 21760;              // 1024
constexpr size_t WS_SHIFT2 = 22784;              // 1024
constexpr size_t WS_AVGBN  = 23808;              // 8192
constexpr size_t WS_MXBN   = 32000;              // 8192
constexpr size_t WS_SATT   = 40192;              // 8192
constexpr size_t WS_AVGO   = 48384;              // 8192
constexpr size_t WS_MAXO   = 56576;              // 8192
constexpr size_t WS_SP     = 64768;              // 8192
constexpr size_t WS_CONSTBD= 72960;              // 2048
constexpr size_t WS_SCALE3 = 75008;              // 256
constexpr size_t WS_SHIFT3 = 75264;              // 256
constexpr size_t WS_PSUM2  = 75520;              // 65536
constexpr size_t WS_PSQ2   = 141056;             // 65536
constexpr size_t WS_PMAX2  = 206592;             // 65536
constexpr size_t WS_PMIN2  = 272128;             // 65536
constexpr size_t WS_PRE    = 337664;             // 2097152
constexpr size_t WS_T1     = 2434816;            // 8388608
constexpr size_t WS_T2     = 10823424;           // 8388608
// total = 19212032 floats ~= 76.8 MB

__device__ __forceinline__ float gelu_exact(float v) {
    return 0.5f * v * (1.0f + erff(v * 0.70710678118654752440f));
}

// ---------------- K1: GEMM1 (M x C = X[M x 256] * W1^T) + bias + GELU ----------------
// X: (8192, 256) row-major, W1: (1024, 256) row-major, out t1: (8192, 1024)
__global__ __launch_bounds__(256) void gemm1_kernel(const float* __restrict__ X,
                                                    const float* __restrict__ W1,
                                                    const float* __restrict__ b1,
                                                    float* __restrict__ t1) {
    __shared__ float As[16][65];   // [kk][row]
    __shared__ float Bs[16][65];   // [kk][col]
    const int tid = threadIdx.y * 16 + threadIdx.x;
    const int row0 = blockIdx.y * 64;
    const int col0 = blockIdx.x * 64;
    float acc[4][4] = {};
    for (int k0 = 0; k0 < 256; k0 += 16) {
        {
            const int e = tid * 4;
            const int r = e >> 4;
            const int kk = e & 15;
            const float4 v = *(const float4*)(X + (size_t)(row0 + r) * 256 + k0 + kk);
            As[kk + 0][r] = v.x; As[kk + 1][r] = v.y; As[kk + 2][r] = v.z; As[kk + 3][r] = v.w;
            const int o = tid >> 2;
            const int kk2 = (tid & 3) * 4;
            const float4 wv = *(const float4*)(W1 + (size_t)(col0 + o) * 256 + k0 + kk2);
            Bs[kk2 + 0][o] = wv.x; Bs[kk2 + 1][o] = wv.y; Bs[kk2 + 2][o] = wv.z; Bs[kk2 + 3][o] = wv.w;
        }
        __syncthreads();
#pragma unroll
        for (int kk = 0; kk < 16; ++kk) {
            float a[4], bb[4];
#pragma unroll
            for (int i = 0; i < 4; ++i) a[i] = As[kk][threadIdx.y * 4 + i];
#pragma unroll
            for (int j = 0; j < 4; ++j) bb[j] = Bs[kk][threadIdx.x * 4 + j];
#pragma unroll
            for (int i = 0; i < 4; ++i)
#pragma unroll
                for (int j = 0; j < 4; ++j)
                    acc[i][j] = fmaf(a[i], bb[j], acc[i][j]);
        }
        __syncthreads();
    }
#pragma unroll
    for (int i = 0; i < 4; ++i) {
        const int r = row0 + threadIdx.y * 4 + i;
#pragma unroll
        for (int j = 0; j < 4; ++j) {
            const int c = col0 + threadIdx.x * 4 + j;
            float v = acc[i][j] + b1[c];
            t1[(size_t)r * C + c] = gelu_exact(v);
        }
    }
}

// ---------------- K2: reduce t1 -> per-channel sum/sq + per-(b,c) sum ----------------
__global__ __launch_bounds__(256) void reduce1_kernel(const float* __restrict__ t1,
                                                      float* __restrict__ ch_sum,
                                                      float* __restrict__ ch_sq,
                                                      float* __restrict__ gap_sum) {
    const int c = blockIdx.x * 256 + threadIdx.x;
    const int b = blockIdx.y;
    const int p0 = blockIdx.z * 128;
    const float* base = t1 + ((size_t)b * P + p0) * C + c;
    float s = 0.f, q = 0.f;
    for (int p = 0; p < 128; ++p) {
        float v = base[(size_t)p * C];
        s += v;
        q = fmaf(v, v, q);
    }
    atomicAdd(&ch_sum[c], s);
    atomicAdd(&ch_sq[c], q);
    atomicAdd(&gap_sum[b * C + c], s);
}

// ---------------- K3: BN1 stats + gap ----------------
__global__ __launch_bounds__(256) void stats1_kernel(const float* __restrict__ ch_sum,
                                                     const float* __restrict__ ch_sq,
                                                     const float* __restrict__ gap_sum,
                                                     const float* __restrict__ g1,
                                                     const float* __restrict__ be1,
                                                     float* __restrict__ scale1,
                                                     float* __restrict__ shift1,
                                                     float* __restrict__ gap) {
    const int c = blockIdx.x * 256 + threadIdx.x;
    const float m = ch_sum[c] * (1.0f / (float)M);
    const float var = ch_sq[c] * (1.0f / (float)M) - m * m;
    const float rstd = rsqrtf(var + EPS);
    const float sc = rstd * g1[c];
    const float sh = be1[c] - m * sc;
    scale1[c] = sc;
    shift1[c] = sh;
    for (int b = 0; b < B; ++b) {
        const float rm = gap_sum[b * C + c] * (1.0f / (float)P);
        gap[b * C + c] = rm * sc + sh;
    }
}

// ---------------- K4: dynamic kernel MLP ----------------
__global__ __launch_bounds__(128) void dynmlp_kernel(const float* __restrict__ gap,
                                                     const float* __restrict__ aw1,
                                                     const float* __restrict__ ab1,
                                                     const float* __restrict__ aw2,
                                                     const float* __restrict__ ab2,
                                                     float* __restrict__ kw) {
    const int b = blockIdx.x;
    const int t = threadIdx.x;
    __shared__ float h1[128];
    __shared__ float logits[9];
    {
        const float* g = gap + b * C;
        const float* w = aw1 + (size_t)t * C;
        float s = ab1[t];
        for (int c = 0; c < C; ++c) s = fmaf(w[c], g[c], s);
        h1[t] = fmaxf(s, 0.f);
    }
    __syncthreads();
    if (t < 9) {
        const float* w2 = aw2 + t * 128;
        float s = ab2[t];
        for (int j = 0; j < 128; ++j) s = fmaf(w2[j], h1[j], s);
        logits[t] = s;
    }
    __syncthreads();
    if (t == 0) {
        float mx = logits[0];
        for (int i = 1; i < 9; ++i) mx = fmaxf(mx, logits[i]);
        float e[9], den = 0.f;
        for (int i = 0; i < 9; ++i) { e[i] = expf(logits[i] - mx); den += e[i]; }
        const float inv = 1.0f / den;
        for (int i = 0; i < 9; ++i) kw[b * 9 + i] = e[i] * inv;
    }
}

// ---------------- K5: dynamic depthwise conv on bn1(t1), then GELU -> t2 ----------------
__global__ __launch_bounds__(256) void dwconv_kernel(const float* __restrict__ t1,
                                                     const float* __restrict__ scale1,
                                                     const float* __restrict__ shift1,
                                                     const float* __restrict__ kw,
                                                     float* __restrict__ t2) {
    const int b = blockIdx.y >> 5;
    const int h = blockIdx.y & 31;
    const int c = blockIdx.x * 256 + threadIdx.x;
    float k[9];
#pragma unroll
    for (int i = 0; i < 9; ++i) k[i] = kw[b * 9 + i];
    const float sc = scale1[c];
    const float sh = shift1[c];
    const float* tb = t1 + (size_t)b * P * C;
    for (int w = 0; w < W; ++w) {
        float acc = 0.f;
#pragma unroll
        for (int i = 0; i < 3; ++i) {
            const int hh = h + i - 1;
            if (hh < 0 || hh >= H) continue;
#pragma unroll
            for (int j = 0; j < 3; ++j) {
                const int ww = w + j - 1;
                if (ww < 0 || ww >= W) continue;
                const float v = tb[((size_t)(hh * W + ww)) * C + c];
                acc = fmaf(k[i * 3 + j], fmaf(v, sc, sh), acc);
            }
        }
        t2[((size_t)b * P + h * W + w) * C + c] = gelu_exact(acc);
    }
}

// ---------------- K6: reduce t2 -> partial sum/sq/max/min ----------------
__global__ __launch_bounds__(256) void reduce2_kernel(const float* __restrict__ t2,
                                                      float* __restrict__ psum,
                                                      float* __restrict__ psq,
                                                      float* __restrict__ pmax,
                                                      float* __restrict__ pmin) {
    const int c = blockIdx.x * 256 + threadIdx.x;
    const int b = blockIdx.y;
    const int pc = blockIdx.z;
    const float* base = t2 + ((size_t)b * P + pc * 128) * C + c;
    float s = 0.f, q = 0.f, mx = -INFINITY, mn = INFINITY;
    for (int p = 0; p < 128; ++p) {
        float v = base[(size_t)p * C];
        s += v;
        q = fmaf(v, v, q);
        mx = fmaxf(mx, v);
        mn = fminf(mn, v);
    }
    const int idx = (b * 8 + pc) * C + c;
    psum[idx] = s; psq[idx] = q; pmax[idx] = mx; pmin[idx] = mn;
}

// ---------------- K7: BN2 stats + per-(b,c) avg/max after bn ----------------
__global__ __launch_bounds__(256) void stats2_kernel(const float* __restrict__ psum,
                                                     const float* __restrict__ psq,
                                                     const float* __restrict__ pmax,
                                                     const float* __restrict__ pmin,
                                                     const float* __restrict__ g2,
                                                     const float* __restrict__ be2,
                                                     float* __restrict__ scale2,
                                                     float* __restrict__ shift2,
                                                     float* __restrict__ avgbn,
                                                     float* __restrict__ mxbn) {
    const int c = blockIdx.x * 256 + threadIdx.x;
    float S = 0.f, Q = 0.f;
    for (int i = 0; i < 64; ++i) { S += psum[i * C + c]; Q += psq[i * C + c]; }
    const float m = S * (1.0f / (float)M);
    const float var = Q * (1.0f / (float)M) - m * m;
    const float rstd = rsqrtf(var + EPS);
    const float sc = rstd * g2[c];
    const float sh = be2[c] - m * sc;
    scale2[c] = sc;
    shift2[c] = sh;
    for (int b = 0; b < B; ++b) {
        float rs = 0.f, rmx = -INFINITY, rmn = INFINITY;
        for (int pc = 0; pc < 8; ++pc) {
            const int i = (b * 8 + pc) * C + c;
            rs += psum[i];
            rmx = fmaxf(rmx, pmax[i]);
            rmn = fminf(rmn, pmin[i]);
        }
        avgbn[b * C + c] = rs * (1.0f / (float)P) * sc + sh;
        mxbn[b * C + c] = (sc >= 0.f ? rmx : rmn) * sc + sh;
    }
}

// ---------------- K8: channel attention ----------------
__global__ __launch_bounds__(256) void chatt_kernel(const float* __restrict__ avgbn,
                                                    const float* __restrict__ mxbn,
                                                    const float* __restrict__ caw1,
                                                    const float* __restrict__ caw2,
                                                    float* __restrict__ s_att) {
    const int b = blockIdx.x;
    const int t = threadIdx.x;
    __shared__ float ha[64], hm[64];
    if (t < 128) {
        const int o = t & 63;
        const float* v = (t < 64) ? (avgbn + b * C) : (mxbn + b * C);
        const float* w = caw1 + (size_t)o * C;
        float s = 0.f;
        for (int c = 0; c < C; ++c) s = fmaf(w[c], v[c], s);
        s = fmaxf(s, 0.f);
        if (t < 64) ha[o] = s; else hm[o] = s;
    }
    __syncthreads();
    for (int c = t; c < C; c += 256) {
        const float* w2 = caw2 + (size_t)c * 64;
        float s = 0.f;
        for (int j = 0; j < 64; ++j) s = fmaf(w2[j], ha[j] + hm[j], s);
        s_att[b * C + c] = 1.0f / (1.0f + expf(-s));
    }
}

// ---------------- K9: per-(b,p) channel avg/max of y3 = s_att * bn2(t2) ----------------
__global__ __launch_bounds__(256) void spstats_kernel(const float* __restrict__ t2,
                                                      const float* __restrict__ scale2,
                                                      const float* __restrict__ shift2,
                                                      const float* __restrict__ s_att,
                                                      float* __restrict__ avg_o,
                                                      float* __restrict__ max_o) {
    const int row = blockIdx.x;       // b*P + p
    const int b = row >> 10;
    const int t = threadIdx.x;
    const float* base = t2 + (size_t)row * C;
    const float* sa = s_att + b * C;
    float s = 0.f, mx = -INFINITY;
    for (int c = t; c < C; c += 256) {
        const float y = (fmaf(base[c], scale2[c], shift2[c])) * sa[c];
        s += y;
        mx = fmaxf(mx, y);
    }
#pragma unroll
    for (int off = 32; off > 0; off >>= 1) {
        s += __shfl_down(s, off);
        mx = fmaxf(mx, __shfl_down(mx, off));
    }
    __shared__ float ss[4], sm[4];
    const int wave = t >> 6, lane = t & 63;
    if (lane == 0) { ss[wave] = s; sm[wave] = mx; }
    __syncthreads();
    if (t == 0) {
        const float S = ss[0] + ss[1] + ss[2] + ss[3];
        const float Mx = fmaxf(fmaxf(sm[0], sm[1]), fmaxf(sm[2], sm[3]));
        avg_o[row] = S * (1.0f / (float)C);
        max_o[row] = Mx;
    }
}

// ---------------- K10: 7x7 spatial conv + sigmoid ----------------
__global__ __launch_bounds__(256) void spconv_kernel(const float* __restrict__ avg_o,
                                                     const float* __restrict__ max_o,
                                                     const float* __restrict__ sw,
                                                     const float* __restrict__ sb,
                                                     float* __restrict__ sp) {
    const int b = blockIdx.x;
    const int t = threadIdx.x;
    __shared__ float pa[P], pm[P], wsh[98];
    for (int i = t; i < P; i += 256) { pa[i] = avg_o[b * P + i]; pm[i] = max_o[b * P + i]; }
    if (t < 98) wsh[t] = sw[t];
    const float sbv = sb[0];
    __syncthreads();
    for (int idx = t; idx < P; idx += 256) {
        const int h = idx >> 5, w = idx & 31;
        float acc = sbv;
#pragma unroll
        for (int i = 0; i < 7; ++i) {
            const int hh = h + i - 3;
            if (hh < 0 || hh >= H) continue;
#pragma unroll
            for (int j = 0; j < 7; ++j) {
                const int ww = w + j - 3;
                if (ww < 0 || ww >= W) continue;
                const int pidx = hh * W + ww;
                acc = fmaf(wsh[i * 7 + j], pa[pidx], acc);
                acc = fmaf(wsh[49 + i * 7 + j], pm[pidx], acc);
            }
        }
        sp[b * P + idx] = 1.0f / (1.0f + expf(-acc));
    }
}

// ---------------- K11: const_bd[b,d] = sum_c pw[d,c] * s_att[b,c] * shift2[c] ----------------
__global__ __launch_bounds__(256) void constbd_kernel(const float* __restrict__ pw,
                                                      const float* __restrict__ s_att,
                                                      const float* __restrict__ shift2,
                                                      float* __restrict__ const_bd) {
    const int b = blockIdx.x;
    const int d = threadIdx.x;
    const float* w = pw + (size_t)d * C;
    const float* sa = s_att + b * C;
    float s = 0.f;
    for (int c = 0; c < C; ++c) s = fmaf(w[c], sa[c] * shift2[c], s);
    const_bd[b * D + d] = s;
}

// ---------------- K12: GEMM2 with fused affine A-load + epilogue -> pre ----------------
// A[row,c] = t2[row,c] * (s_att[b,c]*scale2[c]);  pre[row,d] = sp[row]*(acc + const_bd[b,d]) + pb[d]
__global__ __launch_bounds__(256) void gemm2_kernel(const float* __restrict__ t2,
                                                    const float* __restrict__ s_att,
                                                    const float* __restrict__ scale2,
                                                    const float* __restrict__ pw,
                                                    const float* __restrict__ pb,
                                                    const float* __restrict__ sp,
                                                    const float* __restrict__ const_bd,
                                                    float* __restrict__ pre) {
    __shared__ float As[16][65];
    __shared__ float Bs[16][65];
    const int tid = threadIdx.y * 16 + threadIdx.x;
    const int row0 = blockIdx.y * 64;
    const int col0 = blockIdx.x * 64;
    const int b = row0 >> 10;
    float acc[4][4] = {};
    for (int k0 = 0; k0 < C; k0 += 16) {
        {
            const int e = tid * 4;
            const int r = e >> 4;
            const int kk = e & 15;
            const float4 v = *(const float4*)(t2 + (size_t)(row0 + r) * C + k0 + kk);
            const float4 sa = *(const float4*)(s_att + b * C + k0 + kk);
            const float4 sc = *(const float4*)(scale2 + k0 + kk);
            As[kk + 0][r] = v.x * sa.x * sc.x;
            As[kk + 1][r] = v.y * sa.y * sc.y;
            As[kk + 2][r] = v.z * sa.z * sc.z;
            As[kk + 3][r] = v.w * sa.w * sc.w;
            const int o = tid >> 2;
            const int kk2 = (tid & 3) * 4;
            const float4 wv = *(const float4*)(pw + (size_t)(col0 + o) * C + k0 + kk2);
            Bs[kk2 + 0][o] = wv.x; Bs[kk2 + 1][o] = wv.y; Bs[kk2 + 2][o] = wv.z; Bs[kk2 + 3][o] = wv.w;
        }
        __syncthreads();
#pragma unroll
        for (int kk = 0; kk < 16; ++kk) {
            float a[4], bb[4];
#pragma unroll
            for (int i = 0; i < 4; ++i) a[i] = As[kk][threadIdx.y * 4 + i];
#pragma unroll
            for (int j = 0; j < 4; ++j) bb[j] = Bs[kk][threadIdx.x * 4 + j];
#pragma unroll
            for (int i = 0; i < 4; ++i)
#pragma unroll
                for (int j = 0; j < 4; ++j)
                    acc[i][j] = fmaf(a[i], bb[j], acc[i][j]);
        }
        __syncthreads();
    }
#pragma unroll
    for (int i = 0; i < 4; ++i) {
        const int r = row0 + threadIdx.y * 4 + i;
        const float spr = sp[r];
#pragma unroll
        for (int j = 0; j < 4; ++j) {
            const int d = col0 + threadIdx.x * 4 + j;
            pre[(size_t)r * D + d] = spr * (acc[i][j] + const_bd[b * D + d]) + pb[d];
        }
    }
}

// ---------------- K13: reduce pre -> per-d sum/sq ----------------
__global__ __launch_bounds__(256) void reduce3_kernel(const float* __restrict__ pre,
                                                      float* __restrict__ ch_sum,
                                                      float* __restrict__ ch_sq) {
    const int d = threadIdx.x;
    const int b = blockIdx.y;
    const int pc = blockIdx.z;
    const float* base = pre + ((size_t)b * P + pc * 32) * D + d;
    float s = 0.f, q = 0.f;
    for (int p = 0; p < 32; ++p) {
        float v = base[(size_t)p * D];
        s += v;
        q = fmaf(v, v, q);
    }
    atomicAdd(&ch_sum[d], s);
    atomicAdd(&ch_sq[d], q);
}

// ---------------- K14: BN3 stats ----------------
__global__ __launch_bounds__(256) void stats3_kernel(const float* __restrict__ ch_sum,
                                                     const float* __restrict__ ch_sq,
                                                     const float* __restrict__ g3,
                                                     const float* __restrict__ be3,
                                                     float* __restrict__ scale3,
                                                     float* __restrict__ shift3) {
    const int d = threadIdx.x;
    const float m = ch_sum[d] * (1.0f / (float)M);
    const float var = ch_sq[d] * (1.0f / (float)M) - m * m;
    const float rstd = rsqrtf(var + EPS);
    const float sc = rstd * g3[d];
    scale3[d] = sc;
    shift3[d] = be3[d] - m * sc;
}

// ---------------- K15: final residual add ----------------
__global__ __launch_bounds__(256) void final_kernel(const float* __restrict__ x,
                                                    const float* __restrict__ pre,
                                                    const float* __restrict__ scale3,
                                                    const float* __restrict__ shift3,
                                                    float* __restrict__ out) {
    const int i = blockIdx.x * 256 + threadIdx.x;   // float4 index
    const int e = i * 4;
    const int d = e & 255;
    const float4 xv = *(const float4*)(x + e);
    const float4 pv = *(const float4*)(pre + e);
    const float4 sc = *(const float4*)(scale3 + d);
    const float4 sh = *(const float4*)(shift3 + d);
    float4 o;
    o.x = xv.x + fmaf(pv.x, sc.x, sh.x);
    o.y = xv.y + fmaf(pv.y, sc.y, sh.y);
    o.z = xv.z + fmaf(pv.z, sc.z, sh.z);
    o.w = xv.w + fmaf(pv.w, sc.w, sh.w);
    *(float4*)(out + e) = o;
}

extern "C" void kernel_launch(void* const* d_in, const int* in_sizes, int n_in,
                              void* d_out, int out_size, void* d_ws, size_t ws_size,
                              hipStream_t stream) {
    const float* x    = (const float*)d_in[0];
    const float* w1   = (const float*)d_in[1];
    const float* b1   = (const float*)d_in[2];
    const float* g1   = (const float*)d_in[3];
    const float* be1  = (const float*)d_in[4];
    const float* aw1  = (const float*)d_in[5];
    const float* ab1  = (const float*)d_in[6];
    const float* aw2  = (const float*)d_in[7];
    const float* ab2  = (const float*)d_in[8];
    const float* g2   = (const float*)d_in[9];
    const float* be2  = (const float*)d_in[10];
    const float* caw1 = (const float*)d_in[11];
    const float* caw2 = (const float*)d_in[12];
    const float* pw   = (const float*)d_in[13];
    const float* pb   = (const float*)d_in[14];
    const float* g3   = (const float*)d_in[15];
    const float* be3  = (const float*)d_in[16];
    const float* sw   = (const float*)d_in[17];
    const float* sb   = (const float*)d_in[18];
    float* out = (float*)d_out;
    float* ws = (float*)d_ws;

    // zero atomic accumulators
    hipMemsetAsync(ws, 0, WS_ACC_COUNT * sizeof(float), stream);

    float* t1      = ws + WS_T1;
    float* t2      = ws + WS_T2;
    float* pre     = ws + WS_PRE;
    float* chsum1  = ws + WS_CHSUM1;
    float* chsq1   = ws + WS_CHSQ1;
    float* gapsum  = ws + WS_GAPSUM;
    float* chsum3  = ws + WS_CHSUM3;
    float* chsq3   = ws + WS_CHSQ3;
    float* scale1  = ws + WS_SCALE1;
    float* shift1  = ws + WS_SHIFT1;
    float* gap     = ws + WS_GAP;
    float* kw      = ws + WS_KW;
    float* scale2  = ws + WS_SCALE2;
    float* shift2  = ws + WS_SHIFT2;
    float* avgbn   = ws + WS_AVGBN;
    float* mxbn    = ws + WS_MXBN;
    float* s_att   = ws + WS_SATT;
    float* avg_o   = ws + WS_AVGO;
    float* max_o   = ws + WS_MAXO;
    float* sp      = ws + WS_SP;
    float* constbd = ws + WS_CONSTBD;
    float* scale3  = ws + WS_SCALE3;
    float* shift3  = ws + WS_SHIFT3;
    float* psum2   = ws + WS_PSUM2;
    float* psq2    = ws + WS_PSQ2;
    float* pmax2   = ws + WS_PMAX2;
    float* pmin2   = ws + WS_PMIN2;

    // K1: expand GEMM + GELU
    gemm1_kernel<<<dim3(C / 64, M / 64), dim3(16, 16), 0, stream>>>(x, w1, b1, t1);
    // K2/K3: BN1 stats + gap
    reduce1_kernel<<<dim3(C / 256, B, 8), 256, 0, stream>>>(t1, chsum1, chsq1, gapsum);
    stats1_kernel<<<dim3(C / 256), 256, 0, stream>>>(chsum1, chsq1, gapsum, g1, be1, scale1, shift1, gap);
    // K4: dynamic kernel weights
    dynmlp_kernel<<<dim3(B), 128, 0, stream>>>(gap, aw1, ab1, aw2, ab2, kw);
    // K5: depthwise conv + GELU
    dwconv_kernel<<<dim3(C / 256, B * H), 256, 0, stream>>>(t1, scale1, shift1, kw, t2);
    // K6/K7: BN2 stats + per-(b,c) avg/max
    reduce2_kernel<<<dim3(C / 256, B, 8), 256, 0, stream>>>(t2, psum2, psq2, pmax2, pmin2);
    stats2_kernel<<<dim3(C / 256), 256, 0, stream>>>(psum2, psq2, pmax2, pmin2, g2, be2,
                                                     scale2, shift2, avgbn, mxbn);
    // K8: channel attention
    chatt_kernel<<<dim3(B), 256, 0, stream>>>(avgbn, mxbn, caw1, caw2, s_att);
    // K9: spatial stats
    spstats_kernel<<<dim3(M), 256, 0, stream>>>(t2, scale2, shift2, s_att, avg_o, max_o);
    // K10: 7x7 conv + sigmoid
    spconv_kernel<<<dim3(B), 256, 0, stream>>>(avg_o, max_o, sw, sb, sp);
    // K11: const_bd
    constbd_kernel<<<dim3(B), D, 0, stream>>>(pw, s_att, shift2, constbd);
    // K12: project GEMM + epilogue
    gemm2_kernel<<<dim3(D / 64, M / 64), dim3(16, 16), 0, stream>>>(t2, s_att, scale2, pw, pb,
                                                                    sp, constbd, pre);
    // K13/K14: BN3 stats
    reduce3_kernel<<<dim3(1, B, 32), D, 0, stream>>>(pre, chsum3, chsq3);
    stats3_kernel<<<dim3(1), D, 0, stream>>>(chsum3, chsq3, g3, be3, scale3, shift3);
    // K15: final
    final_kernel<<<dim3((M * D / 4) / 256), 256, 0, stream>>>(x, pre, scale3, shift3, out);
}

// Round 2
// 304.015 us; speedup vs baseline: 1.6092x; 1.6092x over previous
//
#include <hip/hip_runtime.h>
#include <math.h>

// Problem constants
constexpr int B = 8;
constexpr int D = 256;     // model dim
constexpr int C = 1024;    // expanded channels
constexpr int H = 32, W = 32;
constexpr int P = H * W;            // 1024 spatial positions
constexpr int M = B * P;            // 8192 rows
constexpr float EPS = 1e-5f;

typedef unsigned short u16;
typedef unsigned int u32;
typedef __attribute__((ext_vector_type(8))) short short8;
typedef __attribute__((ext_vector_type(4))) float floatx4;

// ---------------- workspace layout (in floats) ----------------
// zeroed accumulator region
constexpr size_t WS_CHSUM1 = 0;                  // 1024
constexpr size_t WS_CHSQ1  = 1024;               // 1024
constexpr size_t WS_GAPSUM = 2048;               // 8192
constexpr size_t WS_CHSUM3 = 10240;              // 256
constexpr size_t WS_CHSQ3  = 10496;              // 256
constexpr size_t WS_ACC_COUNT = 10752;           // total zeroed floats
// non-zeroed
constexpr size_t WS_SCALE1 = 11264;              // 1024
constexpr size_t WS_SHIFT1 = 12288;              // 1024
constexpr size_t WS_GAP    = 13312;              // 8192
constexpr size_t WS_KW     = 21504;              // 72 (pad)
constexpr size_t WS_SCALE2 = 21760;              // 1024
constexpr size_t WS_SHIFT2 = 22784;              // 1024
constexpr size_t WS_AVGBN  = 23808;              // 8192
constexpr size_t WS_MXBN   = 32000;              // 8192
constexpr size_t WS_SATT   = 40192;              // 8192
constexpr size_t WS_AVGO   = 48384;              // 8192
constexpr size_t WS_MAXO   = 56576;              // 8192
constexpr size_t WS_SP     = 64768;              // 8192
constexpr size_t WS_SCALE3 = 75008;              // 256
constexpr size_t WS_SHIFT3 = 75264;              // 256
constexpr size_t WS_PSUM2  = 75520;              // 65536
constexpr size_t WS_PSQ2   = 141056;             // 65536
constexpr size_t WS_PMAX2  = 206592;             // 65536  (aliased later: pwb)
constexpr size_t WS_PMIN2  = 272128;             // 65536  (aliased later: pwb tail)
constexpr size_t WS_PRE    = 337664;             // 2097152 (aliased early: xb + w1b)
constexpr size_t WS_T1     = 2434816;            // 8388608 (aliased later: yb)
constexpr size_t WS_T2     = 10823424;           // 8388608
// total = 19212032 floats ~= 76.8 MB (unchanged from R1)

__device__ __forceinline__ float gelu_exact(float v) {
    return 0.5f * v * (1.0f + erff(v * 0.70710678118654752440f));
}

__device__ __forceinline__ u16 f2bf(float f) {
    u32 u = __float_as_uint(f);
    u += 0x7fff + ((u >> 16) & 1);   // round-to-nearest-even
    return (u16)(u >> 16);
}

// ---------------- cast fp32 -> bf16, 4 elems/thread ----------------
__global__ __launch_bounds__(256) void cvt_bf16_kernel(const float* __restrict__ in,
                                                       u16* __restrict__ out, int n4) {
    const int i = blockIdx.x * 256 + threadIdx.x;
    if (i >= n4) return;
    const float4 v = *(const float4*)(in + (size_t)i * 4);
    uint2 o;
    o.x = ((u32)f2bf(v.x)) | ((u32)f2bf(v.y) << 16);
    o.y = ((u32)f2bf(v.z)) | ((u32)f2bf(v.w) << 16);
    *(uint2*)(out + (size_t)i * 4) = o;
}

// ---------------- MFMA bf16 GEMM: out[M x NS] = A[M x KD] * Bw[N x KD]^T ----------------
// m97-style: 128x128 tile, BK=32, global_load_lds width=16, 4 waves of 64x64.
// EPI 0: out = gelu(acc + bias[col])         (gemm1)
// EPI 1: out = rowscale[row]*acc + bias[col] (gemm2)
template<int KD, int EPI, int NS>
__global__ __launch_bounds__(256) void mfma_gemm_kernel(
    const u16* __restrict__ A,
    const u16* __restrict__ Bw,
    const float* __restrict__ bias,
    const float* __restrict__ rowscale,
    float* __restrict__ out)
{
    __shared__ u16 As[128 * 32];
    __shared__ u16 Bs[128 * 32];
    const int t = threadIdx.x;
    const int lane = t & 63;
    const int row0 = blockIdx.y * 128;
    const int col0 = blockIdx.x * 128;
    const int wv = t >> 6;
    const int wrow = (wv >> 1) * 64;
    const int wcol = (wv & 1) * 64;
    const int lm = lane & 15;
    const int lk8 = (lane >> 4) * 8;

    const int srow = t >> 2;          // 0..63 staging row
    const int scol = (t & 3) * 8;     // staging col (bf16 elems)

    const u16* gA0 = A + (size_t)(row0 + srow) * KD + scol;
    const u16* gA1 = A + (size_t)(row0 + 64 + srow) * KD + scol;
    const u16* gB0 = Bw + (size_t)(col0 + srow) * KD + scol;
    const u16* gB1 = Bw + (size_t)(col0 + 64 + srow) * KD + scol;

    const floatx4 zero = {0.f, 0.f, 0.f, 0.f};
    floatx4 acc[4][4];
#pragma unroll
    for (int i = 0; i < 4; ++i)
#pragma unroll
        for (int j = 0; j < 4; ++j) acc[i][j] = zero;

    for (int k0 = 0; k0 < KD; k0 += 32) {
        __builtin_amdgcn_global_load_lds(
            (const __attribute__((address_space(1))) void*)(gA0 + k0),
            (__attribute__((address_space(3))) void*)(As + t * 8), 16, 0, 0);
        __builtin_amdgcn_global_load_lds(
            (const __attribute__((address_space(1))) void*)(gA1 + k0),
            (__attribute__((address_space(3))) void*)(As + 2048 + t * 8), 16, 0, 0);
        __builtin_amdgcn_global_load_lds(
            (const __attribute__((address_space(1))) void*)(gB0 + k0),
            (__attribute__((address_space(3))) void*)(Bs + t * 8), 16, 0, 0);
        __builtin_amdgcn_global_load_lds(
            (const __attribute__((address_space(1))) void*)(gB1 + k0),
            (__attribute__((address_space(3))) void*)(Bs + 2048 + t * 8), 16, 0, 0);
        __syncthreads();   // drains vmcnt(0) -> staged data visible
        short8 af[4], bf[4];
#pragma unroll
        for (int i = 0; i < 4; ++i)
            af[i] = *(const short8*)(As + (wrow + i * 16 + lm) * 32 + lk8);
#pragma unroll
        for (int j = 0; j < 4; ++j)
            bf[j] = *(const short8*)(Bs + (wcol + j * 16 + lm) * 32 + lk8);
#pragma unroll
        for (int i = 0; i < 4; ++i)
#pragma unroll
            for (int j = 0; j < 4; ++j)
                acc[i][j] = __builtin_amdgcn_mfma_f32_16x16x32_bf16(af[i], bf[j], acc[i][j], 0, 0, 0);
        __syncthreads();   // all waves done with LDS before next stage
    }

    // C/D layout (m89-verified): col = lane&15, row = (lane>>4)*4 + reg
#pragma unroll
    for (int i = 0; i < 4; ++i) {
#pragma unroll
        for (int r = 0; r < 4; ++r) {
            const int grow = row0 + wrow + i * 16 + (lane >> 4) * 4 + r;
            float rs = 0.f;
            if (EPI == 1) rs = rowscale[grow];
#pragma unroll
            for (int j = 0; j < 4; ++j) {
                const int gcol = col0 + wcol + j * 16 + lm;
                const float v = acc[i][j][r];
                if (EPI == 0) {
                    out[(size_t)grow * NS + gcol] = gelu_exact(v + bias[gcol]);
                } else {
                    out[(size_t)grow * NS + gcol] = rs * v + bias[gcol];
                }
            }
        }
    }
}

// ---------------- K2: reduce t1 -> per-channel sum/sq + per-(b,c) sum ----------------
__global__ __launch_bounds__(256) void reduce1_kernel(const float* __restrict__ t1,
                                                      float* __restrict__ ch_sum,
                                                      float* __restrict__ ch_sq,
                                                      float* __restrict__ gap_sum) {
    const int c = blockIdx.x * 256 + threadIdx.x;
    const int b = blockIdx.y;
    const int p0 = blockIdx.z * 128;
    const float* base = t1 + ((size_t)b * P + p0) * C + c;
    float s = 0.f, q = 0.f;
    for (int p = 0; p < 128; ++p) {
        float v = base[(size_t)p * C];
        s += v;
        q = fmaf(v, v, q);
    }
    atomicAdd(&ch_sum[c], s);
    atomicAdd(&ch_sq[c], q);
    atomicAdd(&gap_sum[b * C + c], s);
}

// ---------------- K3: BN1 stats + gap ----------------
__global__ __launch_bounds__(256) void stats1_kernel(const float* __restrict__ ch_sum,
                                                     const float* __restrict__ ch_sq,
                                                     const float* __restrict__ gap_sum,
                                                     const float* __restrict__ g1,
                                                     const float* __restrict__ be1,
                                                     float* __restrict__ scale1,
                                                     float* __restrict__ shift1,
                                                     float* __restrict__ gap) {
    const int c = blockIdx.x * 256 + threadIdx.x;
    const float m = ch_sum[c] * (1.0f / (float)M);
    const float var = ch_sq[c] * (1.0f / (float)M) - m * m;
    const float rstd = rsqrtf(var + EPS);
    const float sc = rstd * g1[c];
    const float sh = be1[c] - m * sc;
    scale1[c] = sc;
    shift1[c] = sh;
    for (int b = 0; b < B; ++b) {
        const float rm = gap_sum[b * C + c] * (1.0f / (float)P);
        gap[b * C + c] = rm * sc + sh;
    }
}

// ---------------- K4: dynamic kernel MLP ----------------
__global__ __launch_bounds__(128) void dynmlp_kernel(const float* __restrict__ gap,
                                                     const float* __restrict__ aw1,
                                                     const float* __restrict__ ab1,
                                                     const float* __restrict__ aw2,
                                                     const float* __restrict__ ab2,
                                                     float* __restrict__ kw) {
    const int b = blockIdx.x;
    const int t = threadIdx.x;
    __shared__ float h1[128];
    __shared__ float logits[9];
    {
        const float* g = gap + b * C;
        const float* w = aw1 + (size_t)t * C;
        float s = ab1[t];
        for (int c = 0; c < C; ++c) s = fmaf(w[c], g[c], s);
        h1[t] = fmaxf(s, 0.f);
    }
    __syncthreads();
    if (t < 9) {
        const float* w2 = aw2 + t * 128;
        float s = ab2[t];
        for (int j = 0; j < 128; ++j) s = fmaf(w2[j], h1[j], s);
        logits[t] = s;
    }
    __syncthreads();
    if (t == 0) {
        float mx = logits[0];
        for (int i = 1; i < 9; ++i) mx = fmaxf(mx, logits[i]);
        float e[9], den = 0.f;
        for (int i = 0; i < 9; ++i) { e[i] = expf(logits[i] - mx); den += e[i]; }
        const float inv = 1.0f / den;
        for (int i = 0; i < 9; ++i) kw[b * 9 + i] = e[i] * inv;
    }
}

// ---------------- K5: dynamic depthwise conv on bn1(t1), then GELU -> t2 ----------------
__global__ __launch_bounds__(256) void dwconv_kernel(const float* __restrict__ t1,
                                                     const float* __restrict__ scale1,
                                                     const float* __restrict__ shift1,
                                                     const float* __restrict__ kw,
                                                     float* __restrict__ t2) {
    const int b = blockIdx.y >> 5;
    const int h = blockIdx.y & 31;
    const int c = blockIdx.x * 256 + threadIdx.x;
    float k[9];
#pragma unroll
    for (int i = 0; i < 9; ++i) k[i] = kw[b * 9 + i];
    const float sc = scale1[c];
    const float sh = shift1[c];
    const float* tb = t1 + (size_t)b * P * C;
    for (int w = 0; w < W; ++w) {
        float acc = 0.f;
#pragma unroll
        for (int i = 0; i < 3; ++i) {
            const int hh = h + i - 1;
            if (hh < 0 || hh >= H) continue;
#pragma unroll
            for (int j = 0; j < 3; ++j) {
                const int ww = w + j - 1;
                if (ww < 0 || ww >= W) continue;
                const float v = tb[((size_t)(hh * W + ww)) * C + c];
                acc = fmaf(k[i * 3 + j], fmaf(v, sc, sh), acc);
            }
        }
        t2[((size_t)b * P + h * W + w) * C + c] = gelu_exact(acc);
    }
}

// ---------------- K6: reduce t2 -> partial sum/sq/max/min ----------------
__global__ __launch_bounds__(256) void reduce2_kernel(const float* __restrict__ t2,
                                                      float* __restrict__ psum,
                                                      float* __restrict__ psq,
                                                      float* __restrict__ pmax,
                                                      float* __restrict__ pmin) {
    const int c = blockIdx.x * 256 + threadIdx.x;
    const int b = blockIdx.y;
    const int pc = blockIdx.z;
    const float* base = t2 + ((size_t)b * P + pc * 128) * C + c;
    float s = 0.f, q = 0.f, mx = -INFINITY, mn = INFINITY;
    for (int p = 0; p < 128; ++p) {
        float v = base[(size_t)p * C];
        s += v;
        q = fmaf(v, v, q);
        mx = fmaxf(mx, v);
        mn = fminf(mn, v);
    }
    const int idx = (b * 8 + pc) * C + c;
    psum[idx] = s; psq[idx] = q; pmax[idx] = mx; pmin[idx] = mn;
}

// ---------------- K7: BN2 stats + per-(b,c) avg/max after bn ----------------
__global__ __launch_bounds__(256) void stats2_kernel(const float* __restrict__ psum,
                                                     const float* __restrict__ psq,
                                                     const float* __restrict__ pmax,
                                                     const float* __restrict__ pmin,
                                                     const float* __restrict__ g2,
                                                     const float* __restrict__ be2,
                                                     float* __restrict__ scale2,
                                                     float* __restrict__ shift2,
                                                     float* __restrict__ avgbn,
                                                     float* __restrict__ mxbn) {
    const int c = blockIdx.x * 256 + threadIdx.x;
    float S = 0.f, Q = 0.f;
    for (int i = 0; i < 64; ++i) { S += psum[i * C + c]; Q += psq[i * C + c]; }
    const float m = S * (1.0f / (float)M);
    const float var = Q * (1.0f / (float)M) - m * m;
    const float rstd = rsqrtf(var + EPS);
    const float sc = rstd * g2[c];
    const float sh = be2[c] - m * sc;
    scale2[c] = sc;
    shift2[c] = sh;
    for (int b = 0; b < B; ++b) {
        float rs = 0.f, rmx = -INFINITY, rmn = INFINITY;
        for (int pc = 0; pc < 8; ++pc) {
            const int i = (b * 8 + pc) * C + c;
            rs += psum[i];
            rmx = fmaxf(rmx, pmax[i]);
            rmn = fminf(rmn, pmin[i]);
        }
        avgbn[b * C + c] = rs * (1.0f / (float)P) * sc + sh;
        mxbn[b * C + c] = (sc >= 0.f ? rmx : rmn) * sc + sh;
    }
}

// ---------------- K8: channel attention ----------------
__global__ __launch_bounds__(256) void chatt_kernel(const float* __restrict__ avgbn,
                                                    const float* __restrict__ mxbn,
                                                    const float* __restrict__ caw1,
                                                    const float* __restrict__ caw2,
                                                    float* __restrict__ s_att) {
    const int b = blockIdx.x;
    const int t = threadIdx.x;
    __shared__ float ha[64], hm[64];
    if (t < 128) {
        const int o = t & 63;
        const float* v = (t < 64) ? (avgbn + b * C) : (mxbn + b * C);
        const float* w = caw1 + (size_t)o * C;
        float s = 0.f;
        for (int c = 0; c < C; ++c) s = fmaf(w[c], v[c], s);
        s = fmaxf(s, 0.f);
        if (t < 64) ha[o] = s; else hm[o] = s;
    }
    __syncthreads();
    for (int c = t; c < C; c += 256) {
        const float* w2 = caw2 + (size_t)c * 64;
        float s = 0.f;
        for (int j = 0; j < 64; ++j) s = fmaf(w2[j], ha[j] + hm[j], s);
        s_att[b * C + c] = 1.0f / (1.0f + expf(-s));
    }
}

// ---------------- K9': y = s_att*bn2(t2) -> bf16 yb + per-row avg/max ----------------
__global__ __launch_bounds__(256) void yq_kernel(const float* __restrict__ t2,
                                                 const float* __restrict__ scale2,
                                                 const float* __restrict__ shift2,
                                                 const float* __restrict__ s_att,
                                                 u16* __restrict__ yb,
                                                 float* __restrict__ avg_o,
                                                 float* __restrict__ max_o) {
    const int row = blockIdx.x;       // b*P + p
    const int b = row >> 10;
    const int t = threadIdx.x;
    const int c0 = t * 4;
    const float4 v  = *(const float4*)(t2 + (size_t)row * C + c0);
    const float4 sc = *(const float4*)(scale2 + c0);
    const float4 sh = *(const float4*)(shift2 + c0);
    const float4 sa = *(const float4*)(s_att + (size_t)b * C + c0);
    const float y0 = fmaf(v.x, sc.x, sh.x) * sa.x;
    const float y1 = fmaf(v.y, sc.y, sh.y) * sa.y;
    const float y2 = fmaf(v.z, sc.z, sh.z) * sa.z;
    const float y3 = fmaf(v.w, sc.w, sh.w) * sa.w;
    uint2 o;
    o.x = ((u32)f2bf(y0)) | ((u32)f2bf(y1) << 16);
    o.y = ((u32)f2bf(y2)) | ((u32)f2bf(y3) << 16);
    *(uint2*)(yb + (size_t)row * C + c0) = o;
    float s = (y0 + y1) + (y2 + y3);
    float mx = fmaxf(fmaxf(y0, y1), fmaxf(y2, y3));
#pragma unroll
    for (int off = 32; off > 0; off >>= 1) {
        s += __shfl_down(s, off);
        mx = fmaxf(mx, __shfl_down(mx, off));
    }
    __shared__ float ss[4], sm[4];
    const int wave = t >> 6, lane = t & 63;
    if (lane == 0) { ss[wave] = s; sm[wave] = mx; }
    __syncthreads();
    if (t == 0) {
        const float S = ss[0] + ss[1] + ss[2] + ss[3];
        const float Mx = fmaxf(fmaxf(sm[0], sm[1]), fmaxf(sm[2], sm[3]));
        avg_o[row] = S * (1.0f / (float)C);
        max_o[row] = Mx;
    }
}

// ---------------- K10: 7x7 spatial conv + sigmoid ----------------
__global__ __launch_bounds__(256) void spconv_kernel(const float* __restrict__ avg_o,
                                                     const float* __restrict__ max_o,
                                                     const float* __restrict__ sw,
                                                     const float* __restrict__ sb,
                                                     float* __restrict__ sp) {
    const int b = blockIdx.x;
    const int t = threadIdx.x;
    __shared__ float pa[P], pm[P], wsh[98];
    for (int i = t; i < P; i += 256) { pa[i] = avg_o[b * P + i]; pm[i] = max_o[b * P + i]; }
    if (t < 98) wsh[t] = sw[t];
    const float sbv = sb[0];
    __syncthreads();
    for (int idx = t; idx < P; idx += 256) {
        const int h = idx >> 5, w = idx & 31;
        float acc = sbv;
#pragma unroll
        for (int i = 0; i < 7; ++i) {
            const int hh = h + i - 3;
            if (hh < 0 || hh >= H) continue;
#pragma unroll
            for (int j = 0; j < 7; ++j) {
                const int ww = w + j - 3;
                if (ww < 0 || ww >= W) continue;
                const int pidx = hh * W + ww;
                acc = fmaf(wsh[i * 7 + j], pa[pidx], acc);
                acc = fmaf(wsh[49 + i * 7 + j], pm[pidx], acc);
            }
        }
        sp[b * P + idx] = 1.0f / (1.0f + expf(-acc));
    }
}

// ---------------- K13: reduce pre -> per-d sum/sq ----------------
__global__ __launch_bounds__(256) void reduce3_kernel(const float* __restrict__ pre,
                                                      float* __restrict__ ch_sum,
                                                      float* __restrict__ ch_sq) {
    const int d = threadIdx.x;
    const int b = blockIdx.y;
    const int pc = blockIdx.z;
    const float* base = pre + ((size_t)b * P + pc * 32) * D + d;
    float s = 0.f, q = 0.f;
    for (int p = 0; p < 32; ++p) {
        float v = base[(size_t)p * D];
        s += v;
        q = fmaf(v, v, q);
    }
    atomicAdd(&ch_sum[d], s);
    atomicAdd(&ch_sq[d], q);
}

// ---------------- K14: BN3 stats ----------------
__global__ __launch_bounds__(256) void stats3_kernel(const float* __restrict__ ch_sum,
                                                     const float* __restrict__ ch_sq,
                                                     const float* __restrict__ g3,
                                                     const float* __restrict__ be3,
                                                     float* __restrict__ scale3,
                                                     float* __restrict__ shift3) {
    const int d = threadIdx.x;
    const float m = ch_sum[d] * (1.0f / (float)M);
    const float var = ch_sq[d] * (1.0f / (float)M) - m * m;
    const float rstd = rsqrtf(var + EPS);
    const float sc = rstd * g3[d];
    scale3[d] = sc;
    shift3[d] = be3[d] - m * sc;
}

// ---------------- K15: final residual add ----------------
__global__ __launch_bounds__(256) void final_kernel(const float* __restrict__ x,
                                                    const float* __restrict__ pre,
                                                    const float* __restrict__ scale3,
                                                    const float* __restrict__ shift3,
                                                    float* __restrict__ out) {
    const int i = blockIdx.x * 256 + threadIdx.x;   // float4 index
    const int e = i * 4;
    const int d = e & 255;
    const float4 xv = *(const float4*)(x + e);
    const float4 pv = *(const float4*)(pre + e);
    const float4 sc = *(const float4*)(scale3 + d);
    const float4 sh = *(const float4*)(shift3 + d);
    float4 o;
    o.x = xv.x + fmaf(pv.x, sc.x, sh.x);
    o.y = xv.y + fmaf(pv.y, sc.y, sh.y);
    o.z = xv.z + fmaf(pv.z, sc.z, sh.z);
    o.w = xv.w + fmaf(pv.w, sc.w, sh.w);
    *(float4*)(out + e) = o;
}

extern "C" void kernel_launch(void* const* d_in, const int* in_sizes, int n_in,
                              void* d_out, int out_size, void* d_ws, size_t ws_size,
                              hipStream_t stream) {
    const float* x    = (const float*)d_in[0];
    const float* w1   = (const float*)d_in[1];
    const float* b1   = (const float*)d_in[2];
    const float* g1   = (const float*)d_in[3];
    const float* be1  = (const float*)d_in[4];
    const float* aw1  = (const float*)d_in[5];
    const float* ab1  = (const float*)d_in[6];
    const float* aw2  = (const float*)d_in[7];
    const float* ab2  = (const float*)d_in[8];
    const float* g2   = (const float*)d_in[9];
    const float* be2  = (const float*)d_in[10];
    const float* caw1 = (const float*)d_in[11];
    const float* caw2 = (const float*)d_in[12];
    const float* pw   = (const float*)d_in[13];
    const float* pb   = (const float*)d_in[14];
    const float* g3   = (const float*)d_in[15];
    const float* be3  = (const float*)d_in[16];
    const float* sw   = (const float*)d_in[17];
    const float* sb   = (const float*)d_in[18];
    float* out = (float*)d_out;
    float* ws = (float*)d_ws;

    // zero atomic accumulators
    hipMemsetAsync(ws, 0, WS_ACC_COUNT * sizeof(float), stream);

    float* t1      = ws + WS_T1;
    float* t2      = ws + WS_T2;
    float* pre     = ws + WS_PRE;
    float* chsum1  = ws + WS_CHSUM1;
    float* chsq1   = ws + WS_CHSQ1;
    float* gapsum  = ws + WS_GAPSUM;
    float* chsum3  = ws + WS_CHSUM3;
    float* chsq3   = ws + WS_CHSQ3;
    float* scale1  = ws + WS_SCALE1;
    float* shift1  = ws + WS_SHIFT1;
    float* gap     = ws + WS_GAP;
    float* kw      = ws + WS_KW;
    float* scale2  = ws + WS_SCALE2;
    float* shift2  = ws + WS_SHIFT2;
    float* avgbn   = ws + WS_AVGBN;
    float* mxbn    = ws + WS_MXBN;
    float* s_att   = ws + WS_SATT;
    float* avg_o   = ws + WS_AVGO;
    float* max_o   = ws + WS_MAXO;
    float* sp      = ws + WS_SP;
    float* scale3  = ws + WS_SCALE3;
    float* shift3  = ws + WS_SHIFT3;
    float* psum2   = ws + WS_PSUM2;
    float* psq2    = ws + WS_PSQ2;
    float* pmax2   = ws + WS_PMAX2;
    float* pmin2   = ws + WS_PMIN2;

    // bf16 aliases (lifetime-disjoint with their hosts):
    u16* xb  = (u16*)(ws + WS_PRE);                 // dead before gemm2 writes pre
    u16* w1b = (u16*)(ws + WS_PRE + 1048576);       // dead before gemm2 writes pre
    u16* pwb = (u16*)(ws + WS_PMAX2);               // written after stats2 (pmax/pmin dead)
    u16* yb  = (u16*)(ws + WS_T1);                  // written after dwconv (t1 dead)

    // casts for GEMM1
    cvt_bf16_kernel<<<dim3((M * 256 / 4) / 256), 256, 0, stream>>>(x, xb, M * 256 / 4);
    cvt_bf16_kernel<<<dim3((C * 256 / 4) / 256), 256, 0, stream>>>(w1, w1b, C * 256 / 4);
    // K1: expand GEMM (bf16 MFMA) + bias + GELU
    mfma_gemm_kernel<256, 0, C><<<dim3(C / 128, M / 128), 256, 0, stream>>>(xb, w1b, b1, nullptr, t1);
    // K2/K3: BN1 stats + gap
    reduce1_kernel<<<dim3(C / 256, B, 8), 256, 0, stream>>>(t1, chsum1, chsq1, gapsum);
    stats1_kernel<<<dim3(C / 256), 256, 0, stream>>>(chsum1, chsq1, gapsum, g1, be1, scale1, shift1, gap);
    // K4: dynamic kernel weights
    dynmlp_kernel<<<dim3(B), 128, 0, stream>>>(gap, aw1, ab1, aw2, ab2, kw);
    // K5: depthwise conv + GELU
    dwconv_kernel<<<dim3(C / 256, B * H), 256, 0, stream>>>(t1, scale1, shift1, kw, t2);
    // K6/K7: BN2 stats + per-(b,c) avg/max
    reduce2_kernel<<<dim3(C / 256, B, 8), 256, 0, stream>>>(t2, psum2, psq2, pmax2, pmin2);
    stats2_kernel<<<dim3(C / 256), 256, 0, stream>>>(psum2, psq2, pmax2, pmin2, g2, be2,
                                                     scale2, shift2, avgbn, mxbn);
    // K8: channel attention
    chatt_kernel<<<dim3(B), 256, 0, stream>>>(avgbn, mxbn, caw1, caw2, s_att);
    // cast pw (after stats2: pmax2/pmin2 region now dead)
    cvt_bf16_kernel<<<dim3((D * C / 4) / 256), 256, 0, stream>>>(pw, pwb, D * C / 4);
    // K9': y quantize + spatial stats
    yq_kernel<<<dim3(M), 256, 0, stream>>>(t2, scale2, shift2, s_att, yb, avg_o, max_o);
    // K10: 7x7 conv + sigmoid
    spconv_kernel<<<dim3(B), 256, 0, stream>>>(avg_o, max_o, sw, sb, sp);
    // K12: project GEMM (bf16 MFMA) + sp/bias epilogue
    mfma_gemm_kernel<1024, 1, D><<<dim3(D / 128, M / 128), 256, 0, stream>>>(yb, pwb, pb, sp, pre);
    // K13/K14: BN3 stats
    reduce3_kernel<<<dim3(1, B, 32), D, 0, stream>>>(pre, chsum3, chsq3);
    stats3_kernel<<<dim3(1), D, 0, stream>>>(chsum3, chsq3, g3, be3, scale3, shift3);
    // K15: final
    final_kernel<<<dim3((M * D / 4) / 256), 256, 0, stream>>>(x, pre, scale3, shift3, out);
}